// Round 9
// baseline (251.252 us; speedup 1.0000x reference)
//
#include <hip/hip_runtime.h>
#include <hip/hip_bf16.h>

#define N_NODES 50000
#define K_NBR   16
#define DIN     128
#define DOUT    64
#define NPB     64   // nodes per block in the linear / fused kernels

typedef __hip_bfloat16 bf16;
typedef __attribute__((ext_vector_type(8))) short bf16x8;
typedef __attribute__((ext_vector_type(4))) float f32x4;

__device__ __forceinline__ float b2f(bf16 v) { return __bfloat162float(v); }
__device__ __forceinline__ float us2f(unsigned short u) {        // bf16 bits -> f32 (exact)
    return __uint_as_float(((unsigned)u) << 16);
}
__device__ __forceinline__ float sigmoidf_(float x) { return 1.0f / (1.0f + __expf(-x)); }
__device__ __forceinline__ short f2bs(float f) {
    bf16 b = __float2bfloat16(f);
    return *reinterpret_cast<short*>(&b);
}
// lane-constant broadcast without touching the DS pipe
__device__ __forceinline__ float readlane_f(float v, int lane) {
    return __uint_as_float(__builtin_amdgcn_readlane(__float_as_uint(v), lane));
}

template <typename T> __device__ __forceinline__ float ld(const T* p, size_t i);
template <> __device__ __forceinline__ float ld<float>(const float* p, size_t i) { return p[i]; }
template <> __device__ __forceinline__ float ld<bf16>(const bf16* p, size_t i)   { return b2f(p[i]); }

template <typename T> __device__ __forceinline__ void st(T* p, size_t i, float v);
template <> __device__ __forceinline__ void st<float>(float* p, size_t i, float v) { p[i] = v; }
template <> __device__ __forceinline__ void st<bf16>(bf16* p, size_t i, float v)   { p[i] = __float2bfloat16(v); }

// A-fragment loaders: 8 k-contiguous bf16 values from a global row.
__device__ __forceinline__ bf16x8 load_a8(const bf16* p) { return *(const bf16x8*)p; }
__device__ __forceinline__ bf16x8 load_a8(const float* p) {
    float4 v0 = *(const float4*)p;
    float4 v1 = *(const float4*)(p + 4);
    bf16x8 r;
    r[0] = f2bs(v0.x); r[1] = f2bs(v0.y); r[2] = f2bs(v0.z); r[3] = f2bs(v0.w);
    r[4] = f2bs(v1.x); r[5] = f2bs(v1.y); r[6] = f2bs(v1.z); r[7] = f2bs(v1.w);
    return r;
}

// ---------------------------------------------------------------------------
// Weight transpose + dtype-detect (fused). flag: 1 = float32, 0 = bf16.
// ---------------------------------------------------------------------------
__global__ __launch_bounds__(256) void wtrans_kernel(
    const void* __restrict__ Wa, const void* __restrict__ Wb,
    const void* __restrict__ Wc, const void* __restrict__ Wd,
    const unsigned short* __restrict__ x1probe,
    unsigned short* __restrict__ wtg, int* __restrict__ flag)
{
    __shared__ unsigned short t[DIN][DOUT + 1];
    __shared__ int cnt;
    if (threadIdx.x == 0) cnt = 0;
    __syncthreads();
    int c = 0;
#pragma unroll
    for (int i = 0; i < 16; ++i) {
        unsigned short w = x1probe[(size_t)(threadIdx.x * 16 + i) * 2];  // low half-word
        int e = (w >> 7) & 0xFF;
        c += (e >= 112 && e <= 142) ? 1 : 0;
    }
    atomicAdd(&cnt, c);
    __syncthreads();
    const int isf32 = (cnt >= 2048) ? 0 : 1;
    if (blockIdx.x == 0 && threadIdx.x == 0) *flag = isf32;

    const void* W = (blockIdx.x == 0 ? Wa : blockIdx.x == 1 ? Wb : blockIdx.x == 2 ? Wc : Wd);
    unsigned short* o = wtg + (size_t)blockIdx.x * DIN * DOUT;
    if (isf32) {
        const float* Wf = (const float*)W;
#pragma unroll 8
        for (int it = 0; it < 32; ++it) {
            int idx = threadIdx.x + 256 * it;           // 8192 elems
            t[idx >> 6][idx & 63] = (unsigned short)f2bs(Wf[idx]);
        }
    } else {
        const unsigned short* Wh = (const unsigned short*)W;
#pragma unroll 8
        for (int it = 0; it < 32; ++it) {
            int idx = threadIdx.x + 256 * it;
            t[idx >> 6][idx & 63] = Wh[idx];
        }
    }
    __syncthreads();
#pragma unroll 8
    for (int it = 0; it < 32; ++it) {
        int idx = threadIdx.x + 256 * it;
        int d = idx >> 7, k = idx & 127;
        o[idx] = t[k][d];                           // coalesced write
    }
}

// ---------------------------------------------------------------------------
// MFMA dual linear (lin1): xnh = bf16(x @ We1), hlo = sigmoid(x @ Ws1) (bf16,
// compact [N][64]). Validated rounds 4-8; ostride parametrizes the o layout.
// ---------------------------------------------------------------------------
template <typename TX, typename TO>
__device__ __forceinline__ void lin_mfma_body(
    const TX* __restrict__ x,                 // [N][128] rows
    const unsigned short* __restrict__ wt2,   // 2 mats of transposed W [d][k], bf16
    bf16* __restrict__ xnh, TO* __restrict__ o, const int ostride,
    unsigned short* __restrict__ wt)          // LDS, 2*64*128 ushorts
{
    const int tid = threadIdx.x;
    const int nbase = blockIdx.x * NPB;

#pragma unroll
    for (int it = 0; it < 8; ++it) {
        int idx = tid + 256 * it;               // 0..2047
        int mt = idx >> 10, rem = idx & 1023;
        int r = rem >> 4, c = rem & 15;
        int4 v = *(const int4*)(wt2 + mt * 8192 + r * DIN + c * 8);
        *(int4*)(wt + mt * 8192 + r * DIN + ((c ^ (r & 15)) << 3)) = v;
    }
    __syncthreads();

    const int w = tid >> 6, lane = tid & 63;
    const int m = lane & 15, g = lane >> 4;

    int arow = nbase + w * 16 + m;
    if (arow >= N_NODES) arow = N_NODES - 1;    // tail: duplicate reads, writes guarded
    const TX* xrow = x + (size_t)arow * DIN;

    f32x4 acc[2][4] = {};
#pragma unroll
    for (int ks = 0; ks < 4; ++ks) {
        bf16x8 a = load_a8(xrow + ks * 32 + g * 8);
        int slot = ((ks * 4 + g) ^ m) << 3;     // 8-ushort slot offset
#pragma unroll
        for (int mt = 0; mt < 2; ++mt)
#pragma unroll
        for (int nc = 0; nc < 4; ++nc) {
            bf16x8 b = *(const bf16x8*)(wt + mt * 8192 + (nc * 16 + m) * DIN + slot);
            acc[mt][nc] = __builtin_amdgcn_mfma_f32_16x16x32_bf16(a, b, acc[mt][nc], 0, 0, 0);
        }
    }

#pragma unroll
    for (int nc = 0; nc < 4; ++nc) {
#pragma unroll
        for (int j = 0; j < 4; ++j) {
            int n = nbase + w * 16 + g * 4 + j;
            if (n < N_NODES) {
                int d = nc * 16 + m;
                xnh[(size_t)n * DOUT + d] = __float2bfloat16(acc[0][nc][j]);
                st(o, (size_t)n * ostride + d, sigmoidf_(acc[1][nc][j]));
            }
        }
    }
}

__global__ __launch_bounds__(256) void lin1_kernel(
    const void* __restrict__ x1, const void* __restrict__ x2,
    const unsigned short* __restrict__ wtg,
    bf16* __restrict__ xnh1, bf16* __restrict__ xnh2,
    bf16* __restrict__ hlo1, bf16* __restrict__ hlo2,
    const int* __restrict__ flag)
{
    __shared__ __align__(16) unsigned short wt[2 * DOUT * DIN];   // 32 KB
    const int g = blockIdx.y;
    const void* x   = g ? x2 : x1;
    bf16*       xnh = g ? xnh2 : xnh1;
    bf16*       hlo = g ? hlo2 : hlo1;
    if (*flag) lin_mfma_body<float, bf16>((const float*)x, wtg, xnh, hlo, DOUT, wt);
    else       lin_mfma_body<bf16,  bf16>((const bf16*)x,  wtg, xnh, hlo, DOUT, wt);
}

// ---------------------------------------------------------------------------
// FUSED aggr1 + lin2 (round 9). 64 nodes per block, 4 waves.
// Phase A (wave = 16 nodes, SGPR-uniform gathers): aggr = (1/K) sum_k
// xnh[nbr[n,k]]; write agh + qq/slo/shi; build the h tile [64][128] bf16 in
// XOR-swizzled LDS (lo half loaded from hlo, hi half = sigmoid(aggr)) --
// h never roundtrips through global (saves 25.6 MB + a launch).
// Phase B: the validated round-5 lin2 MFMA with A-fragments read from the
// LDS h tile (same slot swizzle as the B-side weights, in production since
// round 5). Outputs heh (separate buffer -- must NOT alias xnh, which phase A
// of other blocks still reads) and out[:, :64].
// ---------------------------------------------------------------------------
template <typename TW, typename TO>
__device__ __forceinline__ void aggmm_body(
    const int* __restrict__ nbr, const bf16* __restrict__ xnh,
    const bf16* __restrict__ hlo, const unsigned short* __restrict__ wt2,
    const TW* __restrict__ watt,
    bf16* __restrict__ agh, float* __restrict__ qq, float* __restrict__ slo,
    float* __restrict__ shi, bf16* __restrict__ heh, TO* __restrict__ out,
    unsigned short* __restrict__ ht, unsigned short* __restrict__ wt)
{
    const int tid = threadIdx.x;
    const int w = tid >> 6, lane = tid & 63;
    const int nbase = blockIdx.x * NPB;

    // stage transposed We2/Ws2 (swizzled slots)
#pragma unroll
    for (int it = 0; it < 8; ++it) {
        int idx = tid + 256 * it;
        int mt = idx >> 10, rem = idx & 1023;
        int r = rem >> 4, c = rem & 15;
        int4 v = *(const int4*)(wt2 + mt * 8192 + r * DIN + c * 8);
        *(int4*)(wt + mt * 8192 + r * DIN + ((c ^ (r & 15)) << 3)) = v;
    }

    // ---- phase A: aggregate 16 nodes per wave ----
    float wl = ld(watt, lane);
    float wh = ld(watt, DOUT + lane);
    const unsigned short* __restrict__ xu = (const unsigned short*)xnh;
    const unsigned short* __restrict__ hu = (const unsigned short*)hlo;

#pragma unroll 4
    for (int j = 0; j < 16; ++j) {
        int n = nbase + w * 16 + j;
        int ncl = n < N_NODES ? n : N_NODES - 1;
        const int* __restrict__ nrow = nbr + ncl * K_NBR;    // uniform -> s_load
        unsigned short xv[K_NBR];
#pragma unroll
        for (int k = 0; k < K_NBR; ++k)
            xv[k] = xu[(size_t)nrow[k] * DOUT + lane];       // saddr gathers
        unsigned short hl = hu[(size_t)ncl * DOUT + lane];

        float acc = 0.f;
#pragma unroll
        for (int k = 0; k < K_NBR; ++k) acc += us2f(xv[k]);
        acc *= (1.0f / K_NBR);
        bf16 av16 = __float2bfloat16(acc);
        float av = b2f(av16);

        // h tile, swizzled: row r (r&15 == j), element d stored at slot (d>>3)^j
        const int r = w * 16 + j;
        ht[r * DIN + ((((lane >> 3) ^ j) << 3) | (lane & 7))] = hl;              // d = lane
        ht[r * DIN + (((((lane >> 3) | 8) ^ j) << 3) | (lane & 7))] =
            (unsigned short)f2bs(sigmoidf_(acc));                                 // d = 64+lane

        if (n < N_NODES) agh[(size_t)n * DOUT + lane] = av16;

        float pq = av * av, pl = acc * wl, ph = acc * wh;
#pragma unroll
        for (int off = 1; off < 64; off <<= 1) {
            pq += __shfl_xor(pq, off, 64);
            pl += __shfl_xor(pl, off, 64);
            ph += __shfl_xor(ph, off, 64);
        }
        if (lane == 0 && n < N_NODES) { qq[n] = pq; slo[n] = pl; shi[n] = ph; }
    }
    __syncthreads();   // wt staged by all threads; ht rows are wave-private

    // ---- phase B: dual MFMA on the h tile ----
    const int m = lane & 15, g = lane >> 4;
    f32x4 acc2[2][4] = {};
    const unsigned short* hrow = ht + (w * 16 + m) * DIN;
#pragma unroll
    for (int ks = 0; ks < 4; ++ks) {
        int slot = ((ks * 4 + g) ^ m) << 3;
        bf16x8 a = *(const bf16x8*)(hrow + slot);
#pragma unroll
        for (int mt = 0; mt < 2; ++mt)
#pragma unroll
        for (int nc = 0; nc < 4; ++nc) {
            bf16x8 b = *(const bf16x8*)(wt + mt * 8192 + (nc * 16 + m) * DIN + slot);
            acc2[mt][nc] = __builtin_amdgcn_mfma_f32_16x16x32_bf16(a, b, acc2[mt][nc], 0, 0, 0);
        }
    }
#pragma unroll
    for (int nc = 0; nc < 4; ++nc) {
#pragma unroll
        for (int j2 = 0; j2 < 4; ++j2) {
            int n = nbase + w * 16 + g * 4 + j2;
            if (n < N_NODES) {
                int d = nc * 16 + m;
                heh[(size_t)n * DOUT + d] = __float2bfloat16(acc2[0][nc][j2]);
                st(out, (size_t)n * DIN + d, sigmoidf_(acc2[1][nc][j2]));
            }
        }
    }
}

__global__ __launch_bounds__(256) void aggmm_kernel(
    const int* __restrict__ nbr1, const int* __restrict__ nbr2,
    const bf16* __restrict__ xnh1, const bf16* __restrict__ xnh2,
    const bf16* __restrict__ hlo1, const bf16* __restrict__ hlo2,
    const unsigned short* __restrict__ wtg, const void* __restrict__ watt,
    bf16* __restrict__ agh1, bf16* __restrict__ agh2,
    float* __restrict__ qq1, float* __restrict__ qq2,
    float* __restrict__ slo1, float* __restrict__ slo2,
    float* __restrict__ shi1, float* __restrict__ shi2,
    bf16* __restrict__ heh1, bf16* __restrict__ heh2,
    void* __restrict__ out, const int* __restrict__ flag)
{
    __shared__ __align__(16) unsigned short ht[NPB * DIN];       // 16 KB
    __shared__ __align__(16) unsigned short wt[2 * DOUT * DIN];  // 32 KB
    const int g = blockIdx.y;
    const int*  nbr = g ? nbr2 : nbr1;
    const bf16* xnh = g ? xnh2 : xnh1;
    const bf16* hlo = g ? hlo2 : hlo1;
    bf16*  agh = g ? agh2 : agh1;
    float* qq  = g ? qq2  : qq1;
    float* slo = g ? slo2 : slo1;
    float* shi = g ? shi2 : shi1;
    bf16*  heh = g ? heh2 : heh1;
    const unsigned short* wt2 = wtg + 2 * 8192;   // mats We2, Ws2
    if (*flag)
        aggmm_body<float, float>(nbr, xnh, hlo, wt2, (const float*)watt, agh, qq, slo,
                                 shi, heh, (float*)out + (size_t)g * N_NODES * DIN, ht, wt);
    else
        aggmm_body<bf16, bf16>(nbr, xnh, hlo, wt2, (const bf16*)watt, agh, qq, slo,
                               shi, heh, (bf16*)out + (size_t)g * N_NODES * DIN, ht, wt);
}

// ---------------------------------------------------------------------------
// Pass C+E fused: self-attn + cross-attn + final weighted aggregation.
// One wave per node, zero LDS. Unchanged from round 8 (at its random-gather
// fabric floor: warm replays run identical 62us with 5% HBM).
// ---------------------------------------------------------------------------
template <typename TO>
__device__ __forceinline__ void attn_fused_body(
    const int* __restrict__ nbr1, const int* __restrict__ nbr2,
    const unsigned short* __restrict__ agh1, const unsigned short* __restrict__ agh2,
    const float* __restrict__ qq1, const float* __restrict__ qq2,
    const float* __restrict__ slo1, const float* __restrict__ slo2,
    const float* __restrict__ shi1, const float* __restrict__ shi2,
    const bf16* __restrict__ heh1, const bf16* __restrict__ heh2,
    TO* __restrict__ out)
{
    const int warp = __builtin_amdgcn_readfirstlane(threadIdx.x >> 6);
    const int lane = threadIdx.x & 63;
    const int n = blockIdx.x * 4 + warp;
    const int m = lane & 15, g = lane >> 4;

    // ---- phase 0: issue ALL independent gathers up front ----
    const int* __restrict__ nrow1 = nbr1 + n * K_NBR;   // uniform -> s_load
    const int* __restrict__ nrow2 = nbr2 + n * K_NBR;
    const unsigned short* __restrict__ hu1 = (const unsigned short*)heh1;
    const unsigned short* __restrict__ hu2 = (const unsigned short*)heh2;

    unsigned short hv1[K_NBR], hv2[K_NBR];
#pragma unroll
    for (int k = 0; k < K_NBR; ++k) {
        hv1[k] = hu1[(size_t)nrow1[k] * DOUT + lane];   // saddr gathers, all in flight
        hv2[k] = hu2[(size_t)nrow2[k] * DOUT + lane];
    }

    int idxr = 0;
    if (lane < 32) idxr = ((lane < 16) ? nbr1 : nbr2)[n * K_NBR + m];

    const int i1 = __shfl(idxr, m, 64);
    const int i2 = __shfl(idxr, 16 + m, 64);

    const bf16x8* a1p = (const bf16x8*)(agh1 + (size_t)i1 * DOUT + g * 8);
    const bf16x8* a2p = (const bf16x8*)(agh2 + (size_t)i2 * DOUT + g * 8);
    bf16x8 aA = a1p[0], aB = a1p[4];   // dims 0..31, 32..63 (row i1)
    bf16x8 bA = a2p[0], bB = a2p[4];   // dims 0..31, 32..63 (row i2)

    int myidx = __shfl(idxr, lane & 31, 64);
    const float* pa = (lane < 16) ? qq1 : (lane < 32) ? qq2 : (lane < 48) ? shi1 : shi2;
    float aux = pa[(size_t)myidx];

    // ---- phase 1: attention math ----
    float si  = (lane < 16) ? slo1[n] : slo2[n];
    float sjv = __shfl(aux, 32 + (lane & 31), 64);
    float v = si + sjv;
    v = v > 0.f ? v : 0.01f * v;
    float ev = __expf(v);
    float esum = ev;
#pragma unroll
    for (int off = 1; off < 16; off <<= 1) esum += __shfl_xor(esum, off, 64);

    f32x4 acc = {};
    acc = __builtin_amdgcn_mfma_f32_16x16x32_bf16(aA, bA, acc, 0, 0, 0);
    acc = __builtin_amdgcn_mfma_f32_16x16x32_bf16(aB, bB, acc, 0, 0, 0);

    float q2c = __shfl(aux, 16 + m, 64);
    float s0, s1, s2, s3;
    {
        float q10 = __shfl(aux, g * 4 + 0, 64);
        float q11 = __shfl(aux, g * 4 + 1, 64);
        float q12 = __shfl(aux, g * 4 + 2, 64);
        float q13 = __shfl(aux, g * 4 + 3, 64);
        s0 = __expf(-sqrtf(fmaxf(q10 + q2c - 2.f * acc[0], 1e-12f)));
        s1 = __expf(-sqrtf(fmaxf(q11 + q2c - 2.f * acc[1], 1e-12f)));
        s2 = __expf(-sqrtf(fmaxf(q12 + q2c - 2.f * acc[2], 1e-12f)));
        s3 = __expf(-sqrtf(fmaxf(q13 + q2c - 2.f * acc[3], 1e-12f)));
    }

    float c = s0 + s1 + s2 + s3;
#pragma unroll
    for (int off = 1; off < 16; off <<= 1) {
        s0 += __shfl_xor(s0, off, 64);
        s1 += __shfl_xor(s1, off, 64);
        s2 += __shfl_xor(s2, off, 64);
        s3 += __shfl_xor(s3, off, 64);
    }
    float cs = c;
    cs += __shfl_xor(cs, 16, 64);
    cs += __shfl_xor(cs, 32, 64);
    float tot = cs;
#pragma unroll
    for (int off = 1; off < 16; off <<= 1) tot += __shfl_xor(tot, off, 64);
    float rt = 1.0f / tot;

    float r0 = __shfl(s0, (m >> 2) << 4, 64);
    float r1 = __shfl(s1, (m >> 2) << 4, 64);
    float r2 = __shfl(s2, (m >> 2) << 4, 64);
    float r3 = __shfl(s3, (m >> 2) << 4, 64);
    int mr = m & 3;
    float rsm = mr == 0 ? r0 : mr == 1 ? r1 : mr == 2 ? r2 : r3;

    // norm weights in-register: w1[k] at lane k (g==0), w2[k] at lane 16+k (g==1)
    float wv = (g == 0) ? (rsm * rt * ev / esum)
             : (g == 1) ? (cs  * rt * ev / esum) : 0.f;

    // ---- phase 2: weighted sum over prefetched registers ----
    float acc1 = 0.f, acc2 = 0.f;
#pragma unroll
    for (int k = 0; k < K_NBR; ++k) {
        acc1 += readlane_f(wv, k)      * us2f(hv1[k]);
        acc2 += readlane_f(wv, 16 + k) * us2f(hv2[k]);
    }
    st(out, (size_t)n * DIN + DOUT + lane, sigmoidf_(acc1));                 // graph 1
    st(out, ((size_t)N_NODES + n) * DIN + DOUT + lane, sigmoidf_(acc2));     // graph 2
}

__global__ __launch_bounds__(256) void attn_kernel(
    const int* __restrict__ nbr1, const int* __restrict__ nbr2,
    const unsigned short* __restrict__ agh1, const unsigned short* __restrict__ agh2,
    const float* __restrict__ qq1, const float* __restrict__ qq2,
    const float* __restrict__ slo1, const float* __restrict__ slo2,
    const float* __restrict__ shi1, const float* __restrict__ shi2,
    const bf16* __restrict__ heh1, const bf16* __restrict__ heh2,
    void* __restrict__ out, const int* __restrict__ flag)
{
    if (*flag) attn_fused_body<float>(nbr1, nbr2, agh1, agh2, qq1, qq2, slo1, slo2,
                                      shi1, shi2, heh1, heh2, (float*)out);
    else       attn_fused_body<bf16>(nbr1, nbr2, agh1, agh2, qq1, qq2, slo1, slo2,
                                     shi1, shi2, heh1, heh2, (bf16*)out);
}

// ---------------------------------------------------------------------------
extern "C" void kernel_launch(void* const* d_in, const int* in_sizes, int n_in,
                              void* d_out, int out_size, void* d_ws, size_t ws_size,
                              hipStream_t stream)
{
    const void* x1   = d_in[0];
    const void* x2   = d_in[1];
    const int*  nbr1 = (const int*)d_in[2];
    const int*  nbr2 = (const int*)d_in[3];
    const void* We1  = d_in[4];
    const void* Ws1  = d_in[5];
    const void* We2  = d_in[6];
    const void* Ws2  = d_in[7];
    const void* watt = d_in[8];

    char* ws = (char*)d_ws;
    const size_t SZH = (size_t)N_NODES * DOUT * sizeof(bf16);   // 6.4 MB
    const size_t NSZ = (size_t)N_NODES * sizeof(float);         // 0.2 MB
    bf16* xnh1 = (bf16*)(ws + 0 * SZH);
    bf16* xnh2 = (bf16*)(ws + 1 * SZH);
    bf16* agh1 = (bf16*)(ws + 2 * SZH);
    bf16* agh2 = (bf16*)(ws + 3 * SZH);
    bf16* hlo1 = (bf16*)(ws + 4 * SZH);
    bf16* hlo2 = (bf16*)(ws + 5 * SZH);
    bf16* heh1 = (bf16*)(ws + 6 * SZH);   // must NOT alias xnh (fused kernel)
    bf16* heh2 = (bf16*)(ws + 7 * SZH);
    char* p    =         ws + 8 * SZH;
    int*  flag = (int*)  (p);
    char* aux  =          p + 4096;
    float* qq1  = (float*)(aux + 0 * NSZ);
    float* qq2  = (float*)(aux + 1 * NSZ);
    float* slo1 = (float*)(aux + 2 * NSZ);
    float* slo2 = (float*)(aux + 3 * NSZ);
    float* shi1 = (float*)(aux + 4 * NSZ);
    float* shi2 = (float*)(aux + 5 * NSZ);
    unsigned short* wtg = (unsigned short*)(aux + 6 * NSZ);  // 4 x 16KB transposed bf16 W

    dim3 b(256);
    dim3 gl((N_NODES + NPB - 1) / NPB, 2);   // lin1 / fused aggmm: 64 nodes/block
    dim3 ga(N_NODES / 4);                    // fused attn: 4 node-waves/block

    wtrans_kernel<<<dim3(4), b, 0, stream>>>(We1, Ws1, We2, Ws2,
                                             (const unsigned short*)x1, wtg, flag);
    lin1_kernel <<<gl, b, 0, stream>>>(x1, x2, wtg, xnh1, xnh2, hlo1, hlo2, flag);
    aggmm_kernel<<<gl, b, 0, stream>>>(nbr1, nbr2, xnh1, xnh2, hlo1, hlo2, wtg, watt,
                                       agh1, agh2, qq1, qq2, slo1, slo2, shi1, shi2,
                                       heh1, heh2, d_out, flag);
    attn_kernel <<<ga, b, 0, stream>>>(nbr1, nbr2, (const unsigned short*)agh1,
                                       (const unsigned short*)agh2, qq1, qq2,
                                       slo1, slo2, shi1, shi2, heh1, heh2,
                                       d_out, flag);
}

// Round 10
// 230.064 us; speedup vs baseline: 1.0921x; 1.0921x over previous
//
#include <hip/hip_runtime.h>
#include <hip/hip_bf16.h>

#define N_NODES 50000
#define K_NBR   16
#define DIN     128
#define DOUT    64
#define NPB     64   // nodes per block in the linear kernels

typedef __hip_bfloat16 bf16;
typedef __attribute__((ext_vector_type(8))) short bf16x8;
typedef __attribute__((ext_vector_type(4))) float f32x4;

__device__ __forceinline__ float b2f(bf16 v) { return __bfloat162float(v); }
__device__ __forceinline__ float us2f(unsigned short u) {        // bf16 bits -> f32 (exact)
    return __uint_as_float(((unsigned)u) << 16);
}
__device__ __forceinline__ float sigmoidf_(float x) { return 1.0f / (1.0f + __expf(-x)); }
__device__ __forceinline__ short f2bs(float f) {
    bf16 b = __float2bfloat16(f);
    return *reinterpret_cast<short*>(&b);
}
// lane-constant broadcast without touching the DS pipe
__device__ __forceinline__ float readlane_f(float v, int lane) {
    return __uint_as_float(__builtin_amdgcn_readlane(__float_as_uint(v), lane));
}

template <typename T> __device__ __forceinline__ float ld(const T* p, size_t i);
template <> __device__ __forceinline__ float ld<float>(const float* p, size_t i) { return p[i]; }
template <> __device__ __forceinline__ float ld<bf16>(const bf16* p, size_t i)   { return b2f(p[i]); }

template <typename T> __device__ __forceinline__ void st(T* p, size_t i, float v);
template <> __device__ __forceinline__ void st<float>(float* p, size_t i, float v) { p[i] = v; }
template <> __device__ __forceinline__ void st<bf16>(bf16* p, size_t i, float v)   { p[i] = __float2bfloat16(v); }

// A-fragment loaders: 8 k-contiguous bf16 values from a global row.
__device__ __forceinline__ bf16x8 load_a8(const bf16* p) { return *(const bf16x8*)p; }
__device__ __forceinline__ bf16x8 load_a8(const float* p) {
    float4 v0 = *(const float4*)p;
    float4 v1 = *(const float4*)(p + 4);
    bf16x8 r;
    r[0] = f2bs(v0.x); r[1] = f2bs(v0.y); r[2] = f2bs(v0.z); r[3] = f2bs(v0.w);
    r[4] = f2bs(v1.x); r[5] = f2bs(v1.y); r[6] = f2bs(v1.z); r[7] = f2bs(v1.w);
    return r;
}

// ---------------------------------------------------------------------------
// Weight transpose + dtype-detect (fused). flag: 1 = float32, 0 = bf16.
// ---------------------------------------------------------------------------
__global__ __launch_bounds__(256) void wtrans_kernel(
    const void* __restrict__ Wa, const void* __restrict__ Wb,
    const void* __restrict__ Wc, const void* __restrict__ Wd,
    const unsigned short* __restrict__ x1probe,
    unsigned short* __restrict__ wtg, int* __restrict__ flag)
{
    __shared__ unsigned short t[DIN][DOUT + 1];
    __shared__ int cnt;
    if (threadIdx.x == 0) cnt = 0;
    __syncthreads();
    int c = 0;
#pragma unroll
    for (int i = 0; i < 16; ++i) {
        unsigned short w = x1probe[(size_t)(threadIdx.x * 16 + i) * 2];  // low half-word
        int e = (w >> 7) & 0xFF;
        c += (e >= 112 && e <= 142) ? 1 : 0;
    }
    atomicAdd(&cnt, c);
    __syncthreads();
    const int isf32 = (cnt >= 2048) ? 0 : 1;
    if (blockIdx.x == 0 && threadIdx.x == 0) *flag = isf32;

    const void* W = (blockIdx.x == 0 ? Wa : blockIdx.x == 1 ? Wb : blockIdx.x == 2 ? Wc : Wd);
    unsigned short* o = wtg + (size_t)blockIdx.x * DIN * DOUT;
    if (isf32) {
        const float* Wf = (const float*)W;
#pragma unroll 8
        for (int it = 0; it < 32; ++it) {
            int idx = threadIdx.x + 256 * it;           // 8192 elems
            t[idx >> 6][idx & 63] = (unsigned short)f2bs(Wf[idx]);
        }
    } else {
        const unsigned short* Wh = (const unsigned short*)W;
#pragma unroll 8
        for (int it = 0; it < 32; ++it) {
            int idx = threadIdx.x + 256 * it;
            t[idx >> 6][idx & 63] = Wh[idx];
        }
    }
    __syncthreads();
#pragma unroll 8
    for (int it = 0; it < 32; ++it) {
        int idx = threadIdx.x + 256 * it;
        int d = idx >> 7, k = idx & 127;
        o[idx] = t[k][d];                           // coalesced write
    }
}

// ---------------------------------------------------------------------------
// MFMA dual linear: xnh = bf16(x @ We), o[:, :64] = sigmoid(x @ Ws).
// Validated rounds 4-8.
// ---------------------------------------------------------------------------
template <typename TX, typename TO>
__device__ __forceinline__ void lin_mfma_body(
    const TX* __restrict__ x,                 // [N][128] rows
    const unsigned short* __restrict__ wt2,   // 2 mats of transposed W [d][k], bf16
    bf16* __restrict__ xnh, TO* __restrict__ o,
    unsigned short* __restrict__ wt)          // LDS, 2*64*128 ushorts
{
    const int tid = threadIdx.x;
    const int nbase = blockIdx.x * NPB;

#pragma unroll
    for (int it = 0; it < 8; ++it) {
        int idx = tid + 256 * it;               // 0..2047
        int mt = idx >> 10, rem = idx & 1023;
        int r = rem >> 4, c = rem & 15;
        int4 v = *(const int4*)(wt2 + mt * 8192 + r * DIN + c * 8);
        *(int4*)(wt + mt * 8192 + r * DIN + ((c ^ (r & 15)) << 3)) = v;
    }
    __syncthreads();

    const int w = tid >> 6, lane = tid & 63;
    const int m = lane & 15, g = lane >> 4;

    int arow = nbase + w * 16 + m;
    if (arow >= N_NODES) arow = N_NODES - 1;    // tail: duplicate reads, writes guarded
    const TX* xrow = x + (size_t)arow * DIN;

    f32x4 acc[2][4] = {};
#pragma unroll
    for (int ks = 0; ks < 4; ++ks) {
        bf16x8 a = load_a8(xrow + ks * 32 + g * 8);
        int slot = ((ks * 4 + g) ^ m) << 3;     // 8-ushort slot offset
#pragma unroll
        for (int mt = 0; mt < 2; ++mt)
#pragma unroll
        for (int nc = 0; nc < 4; ++nc) {
            bf16x8 b = *(const bf16x8*)(wt + mt * 8192 + (nc * 16 + m) * DIN + slot);
            acc[mt][nc] = __builtin_amdgcn_mfma_f32_16x16x32_bf16(a, b, acc[mt][nc], 0, 0, 0);
        }
    }

#pragma unroll
    for (int nc = 0; nc < 4; ++nc) {
#pragma unroll
        for (int j = 0; j < 4; ++j) {
            int n = nbase + w * 16 + g * 4 + j;
            if (n < N_NODES) {
                int d = nc * 16 + m;
                xnh[(size_t)n * DOUT + d] = __float2bfloat16(acc[0][nc][j]);
                st(o, (size_t)n * DIN + d, sigmoidf_(acc[1][nc][j]));
            }
        }
    }
}

__global__ __launch_bounds__(256) void lin1_kernel(
    const void* __restrict__ x1, const void* __restrict__ x2,
    const unsigned short* __restrict__ wtg,
    bf16* __restrict__ xnh1, bf16* __restrict__ xnh2,
    bf16* __restrict__ h1, bf16* __restrict__ h2,
    const int* __restrict__ flag)
{
    __shared__ __align__(16) unsigned short wt[2 * DOUT * DIN];   // 32 KB
    const int g = blockIdx.y;
    const void* x   = g ? x2 : x1;
    bf16*       xnh = g ? xnh2 : xnh1;
    bf16*       h   = g ? h2 : h1;
    if (*flag) lin_mfma_body<float, bf16>((const float*)x, wtg, xnh, h, wt);
    else       lin_mfma_body<bf16,  bf16>((const bf16*)x,  wtg, xnh, h, wt);
}

__global__ __launch_bounds__(256) void lin2_kernel(
    const bf16* __restrict__ h1, const bf16* __restrict__ h2,
    const unsigned short* __restrict__ wtg,
    bf16* __restrict__ heh1, bf16* __restrict__ heh2,
    void* __restrict__ out, const int* __restrict__ flag)
{
    __shared__ __align__(16) unsigned short wt[2 * DOUT * DIN];   // 32 KB
    const int g = blockIdx.y;
    const bf16* h   = g ? h2 : h1;
    bf16*       heh = g ? heh2 : heh1;
    if (*flag) lin_mfma_body<bf16, float>(h, wtg + 2 * 8192, heh,
                                          (float*)out + (size_t)g * N_NODES * DIN, wt);
    else       lin_mfma_body<bf16, bf16>(h, wtg + 2 * 8192, heh,
                                         (bf16*)out + (size_t)g * N_NODES * DIN, wt);
}

// ---------------------------------------------------------------------------
// Pass B: aggr = (1/K) sum_k xnh[nbr[n,k]]. SGPR-uniform indexing + gather
// prefetch (rounds 6/8). One wave per node: max TLP for the gather floor
// (round-9 lesson: 16-nodes-per-wave fusion loses the latency hiding).
// ---------------------------------------------------------------------------
template <typename T>
__device__ __forceinline__ void aggr1_body(
    const int* __restrict__ nbr, const bf16* __restrict__ xnh,
    bf16* __restrict__ agh, bf16* __restrict__ h, const T* __restrict__ watt,
    float* __restrict__ qq, float* __restrict__ slo, float* __restrict__ shi)
{
    const int warp = __builtin_amdgcn_readfirstlane(threadIdx.x >> 6);
    const int lane = threadIdx.x & 63;
    const int n = blockIdx.x * 4 + warp;
    const int* __restrict__ nrow = nbr + n * K_NBR;
    const unsigned short* __restrict__ xu = (const unsigned short*)xnh;

    unsigned short xv[K_NBR];
#pragma unroll
    for (int k = 0; k < K_NBR; ++k)
        xv[k] = xu[(size_t)nrow[k] * DOUT + lane];    // uniform saddr, all in flight

    float acc = 0.f;
#pragma unroll
    for (int k = 0; k < K_NBR; ++k) acc += us2f(xv[k]);
    acc *= (1.0f / K_NBR);
    bf16 av16 = __float2bfloat16(acc);
    float av = b2f(av16);
    agh[(size_t)n * DOUT + lane] = av16;
    h[(size_t)n * DIN + DOUT + lane] = __float2bfloat16(sigmoidf_(acc));

    float wl = ld(watt, lane);
    float wh = ld(watt, DOUT + lane);
    float pq = av * av;
    float pl = acc * wl;
    float ph = acc * wh;
#pragma unroll
    for (int off = 1; off < 64; off <<= 1) {
        pq += __shfl_xor(pq, off, 64);
        pl += __shfl_xor(pl, off, 64);
        ph += __shfl_xor(ph, off, 64);
    }
    if (lane == 0) { qq[n] = pq; slo[n] = pl; shi[n] = ph; }
}

__global__ __launch_bounds__(256) void aggr1_kernel(
    const int* __restrict__ nbr1, const int* __restrict__ nbr2,
    const bf16* __restrict__ xnh1, const bf16* __restrict__ xnh2,
    bf16* __restrict__ agh1, bf16* __restrict__ agh2,
    bf16* __restrict__ h1, bf16* __restrict__ h2,
    const void* __restrict__ watt,
    float* __restrict__ qq1, float* __restrict__ qq2,
    float* __restrict__ slo1, float* __restrict__ slo2,
    float* __restrict__ shi1, float* __restrict__ shi2,
    const int* __restrict__ flag)
{
    const int g = blockIdx.y;
    const int*  nbr = g ? nbr2 : nbr1;
    const bf16* xnh = g ? xnh2 : xnh1;
    bf16*       agh = g ? agh2 : agh1;
    bf16*       h   = g ? h2 : h1;
    float* qq  = g ? qq2  : qq1;
    float* slo = g ? slo2 : slo1;
    float* shi = g ? shi2 : shi1;
    if (*flag) aggr1_body<float>(nbr, xnh, agh, h, (const float*)watt, qq, slo, shi);
    else       aggr1_body<bf16>(nbr, xnh, agh, h, (const bf16*)watt,  qq, slo, shi);
}

// ---------------------------------------------------------------------------
// Pass C+E fused: self-attn + cross-attn + final weighted aggregation.
// One wave per node, zero LDS. At the random-gather fabric floor (round-8
// evidence: warm replays identical at 5% HBM; prefetch null).
// ---------------------------------------------------------------------------
template <typename TO>
__device__ __forceinline__ void attn_fused_body(
    const int* __restrict__ nbr1, const int* __restrict__ nbr2,
    const unsigned short* __restrict__ agh1, const unsigned short* __restrict__ agh2,
    const float* __restrict__ qq1, const float* __restrict__ qq2,
    const float* __restrict__ slo1, const float* __restrict__ slo2,
    const float* __restrict__ shi1, const float* __restrict__ shi2,
    const bf16* __restrict__ heh1, const bf16* __restrict__ heh2,
    TO* __restrict__ out)
{
    const int warp = __builtin_amdgcn_readfirstlane(threadIdx.x >> 6);
    const int lane = threadIdx.x & 63;
    const int n = blockIdx.x * 4 + warp;
    const int m = lane & 15, g = lane >> 4;

    // ---- phase 0: issue ALL independent gathers up front ----
    const int* __restrict__ nrow1 = nbr1 + n * K_NBR;   // uniform -> s_load
    const int* __restrict__ nrow2 = nbr2 + n * K_NBR;
    const unsigned short* __restrict__ hu1 = (const unsigned short*)heh1;
    const unsigned short* __restrict__ hu2 = (const unsigned short*)heh2;

    unsigned short hv1[K_NBR], hv2[K_NBR];
#pragma unroll
    for (int k = 0; k < K_NBR; ++k) {
        hv1[k] = hu1[(size_t)nrow1[k] * DOUT + lane];   // saddr gathers, all in flight
        hv2[k] = hu2[(size_t)nrow2[k] * DOUT + lane];
    }

    int idxr = 0;
    if (lane < 32) idxr = ((lane < 16) ? nbr1 : nbr2)[n * K_NBR + m];

    const int i1 = __shfl(idxr, m, 64);
    const int i2 = __shfl(idxr, 16 + m, 64);

    const bf16x8* a1p = (const bf16x8*)(agh1 + (size_t)i1 * DOUT + g * 8);
    const bf16x8* a2p = (const bf16x8*)(agh2 + (size_t)i2 * DOUT + g * 8);
    bf16x8 aA = a1p[0], aB = a1p[4];   // dims 0..31, 32..63 (row i1)
    bf16x8 bA = a2p[0], bB = a2p[4];   // dims 0..31, 32..63 (row i2)

    int myidx = __shfl(idxr, lane & 31, 64);
    const float* pa = (lane < 16) ? qq1 : (lane < 32) ? qq2 : (lane < 48) ? shi1 : shi2;
    float aux = pa[(size_t)myidx];

    // ---- phase 1: attention math (hides phase-0 latency) ----
    float si  = (lane < 16) ? slo1[n] : slo2[n];
    float sjv = __shfl(aux, 32 + (lane & 31), 64);
    float v = si + sjv;
    v = v > 0.f ? v : 0.01f * v;
    float ev = __expf(v);
    float esum = ev;
#pragma unroll
    for (int off = 1; off < 16; off <<= 1) esum += __shfl_xor(esum, off, 64);

    f32x4 acc = {};
    acc = __builtin_amdgcn_mfma_f32_16x16x32_bf16(aA, bA, acc, 0, 0, 0);
    acc = __builtin_amdgcn_mfma_f32_16x16x32_bf16(aB, bB, acc, 0, 0, 0);

    float q2c = __shfl(aux, 16 + m, 64);
    float s0, s1, s2, s3;
    {
        float q10 = __shfl(aux, g * 4 + 0, 64);
        float q11 = __shfl(aux, g * 4 + 1, 64);
        float q12 = __shfl(aux, g * 4 + 2, 64);
        float q13 = __shfl(aux, g * 4 + 3, 64);
        s0 = __expf(-sqrtf(fmaxf(q10 + q2c - 2.f * acc[0], 1e-12f)));
        s1 = __expf(-sqrtf(fmaxf(q11 + q2c - 2.f * acc[1], 1e-12f)));
        s2 = __expf(-sqrtf(fmaxf(q12 + q2c - 2.f * acc[2], 1e-12f)));
        s3 = __expf(-sqrtf(fmaxf(q13 + q2c - 2.f * acc[3], 1e-12f)));
    }

    float c = s0 + s1 + s2 + s3;
#pragma unroll
    for (int off = 1; off < 16; off <<= 1) {
        s0 += __shfl_xor(s0, off, 64);
        s1 += __shfl_xor(s1, off, 64);
        s2 += __shfl_xor(s2, off, 64);
        s3 += __shfl_xor(s3, off, 64);
    }
    float cs = c;
    cs += __shfl_xor(cs, 16, 64);
    cs += __shfl_xor(cs, 32, 64);
    float tot = cs;
#pragma unroll
    for (int off = 1; off < 16; off <<= 1) tot += __shfl_xor(tot, off, 64);
    float rt = 1.0f / tot;

    float r0 = __shfl(s0, (m >> 2) << 4, 64);
    float r1 = __shfl(s1, (m >> 2) << 4, 64);
    float r2 = __shfl(s2, (m >> 2) << 4, 64);
    float r3 = __shfl(s3, (m >> 2) << 4, 64);
    int mr = m & 3;
    float rsm = mr == 0 ? r0 : mr == 1 ? r1 : mr == 2 ? r2 : r3;

    // norm weights in-register: w1[k] at lane k (g==0), w2[k] at lane 16+k (g==1)
    float wv = (g == 0) ? (rsm * rt * ev / esum)
             : (g == 1) ? (cs  * rt * ev / esum) : 0.f;

    // ---- phase 2: weighted sum over prefetched registers ----
    float acc1 = 0.f, acc2 = 0.f;
#pragma unroll
    for (int k = 0; k < K_NBR; ++k) {
        acc1 += readlane_f(wv, k)      * us2f(hv1[k]);
        acc2 += readlane_f(wv, 16 + k) * us2f(hv2[k]);
    }
    st(out, (size_t)n * DIN + DOUT + lane, sigmoidf_(acc1));                 // graph 1
    st(out, ((size_t)N_NODES + n) * DIN + DOUT + lane, sigmoidf_(acc2));     // graph 2
}

__global__ __launch_bounds__(256) void attn_kernel(
    const int* __restrict__ nbr1, const int* __restrict__ nbr2,
    const unsigned short* __restrict__ agh1, const unsigned short* __restrict__ agh2,
    const float* __restrict__ qq1, const float* __restrict__ qq2,
    const float* __restrict__ slo1, const float* __restrict__ slo2,
    const float* __restrict__ shi1, const float* __restrict__ shi2,
    const bf16* __restrict__ heh1, const bf16* __restrict__ heh2,
    void* __restrict__ out, const int* __restrict__ flag)
{
    if (*flag) attn_fused_body<float>(nbr1, nbr2, agh1, agh2, qq1, qq2, slo1, slo2,
                                      shi1, shi2, heh1, heh2, (float*)out);
    else       attn_fused_body<bf16>(nbr1, nbr2, agh1, agh2, qq1, qq2, slo1, slo2,
                                     shi1, shi2, heh1, heh2, (bf16*)out);
}

// ---------------------------------------------------------------------------
extern "C" void kernel_launch(void* const* d_in, const int* in_sizes, int n_in,
                              void* d_out, int out_size, void* d_ws, size_t ws_size,
                              hipStream_t stream)
{
    const void* x1   = d_in[0];
    const void* x2   = d_in[1];
    const int*  nbr1 = (const int*)d_in[2];
    const int*  nbr2 = (const int*)d_in[3];
    const void* We1  = d_in[4];
    const void* Ws1  = d_in[5];
    const void* We2  = d_in[6];
    const void* Ws2  = d_in[7];
    const void* watt = d_in[8];

    char* ws = (char*)d_ws;
    const size_t SZH  = (size_t)N_NODES * DOUT * sizeof(bf16);   // 6.4 MB
    const size_t HSZ  = (size_t)N_NODES * DIN * sizeof(bf16);    // 12.8 MB
    const size_t NSZ  = (size_t)N_NODES * sizeof(float);         //  0.2 MB
    bf16* xnh1 = (bf16*)(ws + 0 * SZH);   // later reused as heh1
    bf16* xnh2 = (bf16*)(ws + 1 * SZH);   // later reused as heh2
    bf16* agh1 = (bf16*)(ws + 2 * SZH);
    bf16* agh2 = (bf16*)(ws + 3 * SZH);
    bf16* h1   = (bf16*)(ws + 4 * SZH);
    bf16* h2   = (bf16*)(ws + 4 * SZH + HSZ);
    char* p    =         ws + 4 * SZH + 2 * HSZ;
    int*  flag = (int*)  (p);
    char* aux  =          p + 4096;
    float* qq1  = (float*)(aux + 0 * NSZ);
    float* qq2  = (float*)(aux + 1 * NSZ);
    float* slo1 = (float*)(aux + 2 * NSZ);
    float* slo2 = (float*)(aux + 3 * NSZ);
    float* shi1 = (float*)(aux + 4 * NSZ);
    float* shi2 = (float*)(aux + 5 * NSZ);
    unsigned short* wtg = (unsigned short*)(aux + 6 * NSZ);  // 4 x 16KB transposed bf16 W

    dim3 b(256);
    dim3 g4(N_NODES / 4, 2);                       // aggr1: 1 wave/node
    dim3 gl((N_NODES + NPB - 1) / NPB, 2);         // linear kernels: 64 nodes/block
    dim3 ga(N_NODES / 4);                          // fused attn: 4 node-waves/block

    wtrans_kernel<<<dim3(4), b, 0, stream>>>(We1, Ws1, We2, Ws2,
                                             (const unsigned short*)x1, wtg, flag);
    lin1_kernel <<<gl, b, 0, stream>>>(x1, x2, wtg, xnh1, xnh2, h1, h2, flag);
    aggr1_kernel<<<g4, b, 0, stream>>>(nbr1, nbr2, xnh1, xnh2, agh1, agh2, h1, h2,
                                       watt, qq1, qq2, slo1, slo2, shi1, shi2, flag);
    lin2_kernel <<<gl, b, 0, stream>>>(h1, h2, wtg, xnh1, xnh2, d_out, flag);
    attn_kernel <<<ga, b, 0, stream>>>(nbr1, nbr2, (const unsigned short*)agh1,
                                       (const unsigned short*)agh2, qq1, qq2,
                                       slo1, slo2, shi1, shi2, xnh1, xnh2,
                                       d_out, flag);
}